// Round 1
// baseline (619.662 us; speedup 1.0000x reference)
//
#include <hip/hip_runtime.h>
#include <hip/hip_bf16.h>

typedef __bf16 bf16_t;
typedef __bf16 bf16x8 __attribute__((ext_vector_type(8)));
typedef __bf16 bf16x4 __attribute__((ext_vector_type(4)));
typedef float f32x4 __attribute__((ext_vector_type(4)));

constexpr int kN = 512;       // nodes per sample
constexpr int kBZ = 32;       // batch
constexpr int kTC = 256;
constexpr int kF1 = 256;
constexpr int kF2 = 128;
constexpr int kE = 524288;
constexpr int kNTOT = 16384;  // kBZ*kN

// ---------------- small utility kernels ----------------

__global__ __launch_bounds__(256) void k_zero(int* p, int n) {
    int i = blockIdx.x * 256 + threadIdx.x;
    if (i < n) p[i] = 0;
}

__global__ __launch_bounds__(256) void k_cvt(const float* __restrict__ in, bf16_t* __restrict__ out, int n4) {
    int i = blockIdx.x * 256 + threadIdx.x;
    if (i < n4) {
        float4 v = ((const float4*)in)[i];
        bf16x4 o = {(bf16_t)v.x, (bf16_t)v.y, (bf16_t)v.z, (bf16_t)v.w};
        ((bf16x4*)out)[i] = o;
    }
}

// P0=ls0+b0, P1=ls1+b1, Q0=lr0, Q1=lr1 per row (u = relu(t))
__global__ __launch_bounds__(256) void k_lsr(const float* __restrict__ tin, const float* __restrict__ fcw,
                                             const float* __restrict__ fcb, float4* __restrict__ lsr) {
    int row = blockIdx.x * 4 + (threadIdx.x >> 6);
    int lane = threadIdx.x & 63;
    const float* tr = tin + (size_t)row * kTC;
    float s0 = 0, s1 = 0, r0 = 0, r1 = 0;
    for (int k = lane; k < kTC; k += 64) {
        float u = fmaxf(tr[k], 0.f);
        s0 += u * fcw[k];        // Ws[0][k] = fc_cat_w[0][0:256]
        s1 += u * fcw[512 + k];  // Ws[1][k]
        r0 += u * fcw[256 + k];  // Wr[0][k]
        r1 += u * fcw[768 + k];  // Wr[1][k]
    }
#pragma unroll
    for (int off = 32; off > 0; off >>= 1) {
        s0 += __shfl_down(s0, off); s1 += __shfl_down(s1, off);
        r0 += __shfl_down(r0, off); r1 += __shfl_down(r1, off);
    }
    if (lane == 0) lsr[row] = make_float4(s0 + fcb[0], s1 + fcb[1], r0, r1);
}

// Ah_T[s][j][i] = (argmax_k(lr[i,k]+ls[j,k]+b[k]+g[i,j,k]) == 0) + (i==j), bf16 {0,1,2}
__global__ __launch_bounds__(256) void k_adj(const float* __restrict__ gum, const float4* __restrict__ lsr,
                                             bf16_t* __restrict__ AT) {
    int s = blockIdx.z;
    int a0 = blockIdx.y * 64, b0 = blockIdx.x * 64;
    __shared__ bf16_t tile[64][72];
    int t = threadIdx.x;
    int lb = t & 63, ra = t >> 6;
    int b = b0 + lb;
    float4 pb = lsr[s * kN + b];  // P0,P1 for column j=b
#pragma unroll 4
    for (int p = 0; p < 16; p++) {
        int a = a0 + p * 4 + ra;
        float4 qa = lsr[s * kN + a];  // Q0,Q1 for row i=a
        const float* g = gum + ((((size_t)s * kN + a) * kN + b) << 1);
        float u0 = fmaxf(g[0], 1e-9f);  // upper clip (1-1e-9) rounds to 1.0f: no-op, u<1
        float u1 = fmaxf(g[1], 1e-9f);
        float g0 = -__logf(-__logf(u0));
        float g1 = -__logf(-__logf(u1));
        float v = ((qa.z + pb.x + g0) >= (qa.w + pb.y + g1)) ? 1.f : 0.f;
        if (a == b) v += 1.f;  // fold self-loop (Ah = A + I)
        tile[lb][p * 4 + ra] = (bf16_t)v;  // transposed: tile[b_local][a_local]
    }
    __syncthreads();
    int rj = t >> 3, li = (t & 7) * 8;
#pragma unroll
    for (int p = 0; p < 2; p++) {
        int j = p * 32 + rj;
        *(bf16x8*)(AT + ((size_t)s * kN + b0 + j) * kN + a0 + li) = *(const bf16x8*)&tile[j][li];
    }
}

// dis_d[row] = rsqrt(row-sum of Ah_T) — deg includes self loop, exact small ints
__global__ __launch_bounds__(256) void k_degdis(const bf16_t* __restrict__ AT, float* __restrict__ dis) {
    int row = blockIdx.x * 4 + (threadIdx.x >> 6);
    int lane = threadIdx.x & 63;
    bf16x8 v = *(const bf16x8*)(AT + (size_t)row * kN + lane * 8);
    float s = 0;
#pragma unroll
    for (int i = 0; i < 8; i++) s += (float)v[i];
#pragma unroll
    for (int off = 32; off > 0; off >>= 1) s += __shfl_down(s, off);
    if (lane == 0) dis[row] = rsqrtf(s);
}

// ---------------- bf16 NT GEMM: C(MxN) = A(MxK) * B(NxK)^T, 128x128 tile, BK=64 ----------------
// MODE 0: C = acc (bf16). MODE 1: C = relu(scale[row]*acc + bias[col]). MODE 2: no relu.
template <int MODE>
__global__ __launch_bounds__(256) void k_gemm(const bf16_t* __restrict__ A, const bf16_t* __restrict__ B,
                                              bf16_t* __restrict__ C, int K, int lda, int ldb, int ldc,
                                              size_t sA, size_t sB, size_t sC,
                                              const float* __restrict__ scale, const float* __restrict__ bias) {
    int m0 = blockIdx.x * 128, n0 = blockIdx.y * 128, s = blockIdx.z;
    A += sA * s; B += sB * s; C += sC * s;
    __shared__ bf16_t As[128][72], Bs[128][72];  // +8 pad: 2-way max on frag reads
    f32x4 acc[4][4] = {};
    int tid = threadIdx.x;
    int wave = tid >> 6, lane = tid & 63;
    int wm = (wave & 1) * 64, wn = (wave >> 1) * 64;
    int fm = lane & 15, fq = lane >> 4;
    int srow = tid >> 3, scol = (tid & 7) * 8;
    for (int kb = 0; kb < K; kb += 64) {
        __syncthreads();
#pragma unroll
        for (int p = 0; p < 4; p++) {
            int row = p * 32 + srow;
            *(uint4*)&As[row][scol] = *(const uint4*)(A + (size_t)(m0 + row) * lda + kb + scol);
            *(uint4*)&Bs[row][scol] = *(const uint4*)(B + (size_t)(n0 + row) * ldb + kb + scol);
        }
        __syncthreads();
#pragma unroll
        for (int kk = 0; kk < 2; kk++) {
            bf16x8 af[4], bfr[4];
#pragma unroll
            for (int i = 0; i < 4; i++) {
                af[i] = *(const bf16x8*)&As[wm + i * 16 + fm][kk * 32 + fq * 8];
                bfr[i] = *(const bf16x8*)&Bs[wn + i * 16 + fm][kk * 32 + fq * 8];
            }
#pragma unroll
            for (int i = 0; i < 4; i++)
#pragma unroll
                for (int j = 0; j < 4; j++)
                    acc[i][j] = __builtin_amdgcn_mfma_f32_16x16x32_bf16(af[i], bfr[j], acc[i][j], 0, 0, 0);
        }
    }
    // C/D layout: col = lane&15, row = (lane>>4)*4 + r  [measured m89/m91]
#pragma unroll
    for (int i = 0; i < 4; i++) {
#pragma unroll
        for (int r = 0; r < 4; r++) {
            int row = wm + i * 16 + fq * 4 + r;
            float sc = 1.f;
            if constexpr (MODE != 0) sc = scale[(size_t)s * kN + m0 + row];
#pragma unroll
            for (int j = 0; j < 4; j++) {
                int col = n0 + wn + j * 16 + fm;
                float v = acc[i][j][r];
                if constexpr (MODE == 1) v = fmaxf(sc * v + bias[col], 0.f);
                if constexpr (MODE == 2) v = sc * v + bias[col];
                C[(size_t)(m0 + row) * ldc + col] = (bf16_t)v;
            }
        }
    }
}

// ZT[s][f][i] = bf16(dis[s,i] * XW[s*512+i, f]) — scale + transpose via LDS tile
template <int F>
__global__ __launch_bounds__(256) void k_scaleT(const bf16_t* __restrict__ XW, const float* __restrict__ dis,
                                                bf16_t* __restrict__ ZT) {
    int s = blockIdx.z, i0 = blockIdx.y * 64, f0 = blockIdx.x * 64;
    __shared__ bf16_t tile[64][72];
    int t = threadIdx.x;
    int gi = t >> 3, gc = (t & 7) * 8;
#pragma unroll
    for (int p = 0; p < 2; p++) {
        int i = p * 32 + gi;
        bf16x8 v = *(const bf16x8*)(XW + (size_t)(s * kN + i0 + i) * F + f0 + gc);
        float d = dis[s * kN + i0 + i];
#pragma unroll
        for (int q = 0; q < 8; q++) tile[gc + q][i] = (bf16_t)(d * (float)v[q]);
    }
    __syncthreads();
#pragma unroll
    for (int p = 0; p < 2; p++) {
        int f = p * 32 + gi;
        *(bf16x8*)(ZT + (size_t)(s * F + f0 + f) * kN + i0 + gc) = *(const bf16x8*)&tile[f][gc];
    }
}

// ---------------- sparse path ----------------

__global__ __launch_bounds__(256) void k_hist(const int* __restrict__ col, int* __restrict__ counts) {
    int e = blockIdx.x * 256 + threadIdx.x;
    if (e < kE) atomicAdd(&counts[col[e]], 1);
}

__global__ __launch_bounds__(256) void k_scan(const int* __restrict__ counts, int* __restrict__ offsets,
                                              int* __restrict__ cursor, float* __restrict__ dis_s) {
    __shared__ int sums[256];
    int t = threadIdx.x;
    int s = 0;
    for (int i = 0; i < 64; i++) s += counts[t * 64 + i];
    sums[t] = s;
    __syncthreads();
    for (int off = 1; off < 256; off <<= 1) {
        int y = (t >= off) ? sums[t - off] : 0;
        __syncthreads();
        sums[t] += y;
        __syncthreads();
    }
    int run = sums[t] - s;  // exclusive prefix
    for (int i = 0; i < 64; i++) {
        int j = t * 64 + i;
        int c = counts[j];
        offsets[j] = run;
        cursor[j] = run;
        dis_s[j] = rsqrtf((float)(c + 1));  // deg includes self loop
        run += c;
    }
}

__global__ __launch_bounds__(256) void k_fill(const int* __restrict__ row, const int* __restrict__ col,
                                              int* __restrict__ cursor, int* __restrict__ list) {
    int e = blockIdx.x * 256 + threadIdx.x;
    if (e < kE) {
        int p = atomicAdd(&cursor[col[e]], 1);
        list[p] = row[e];
    }
}

// out[j,f] = (dis_j * (sum_e dis_r*XW[r,f] + dis_j*XW[j,f]) + bias[f]) [relu?] -> OUT row j, ld 256
template <int F, bool RELU>
__global__ __launch_bounds__(256) void k_sagg(const bf16_t* __restrict__ XW, int rowOffIn,
                                              const int* __restrict__ list, const int* __restrict__ offsets,
                                              const int* __restrict__ counts, const float* __restrict__ dis_s,
                                              const float* __restrict__ bias, bf16_t* __restrict__ OUT,
                                              int outColOff) {
    constexpr int RPB = 256 / F;
    int j = blockIdx.x * RPB + threadIdx.x / F;
    int f = threadIdx.x % F;
    float dj = dis_s[j];
    const bf16_t* base = XW + (size_t)rowOffIn * F;
    float acc = dj * (float)base[(size_t)j * F + f];  // self loop
    int off = offsets[j], cnt = counts[j];
    int q = 0;
    for (; q + 4 <= cnt; q += 4) {  // 4 gathers in flight
        int r0 = list[off + q], r1 = list[off + q + 1], r2 = list[off + q + 2], r3 = list[off + q + 3];
        float a0 = dis_s[r0] * (float)base[(size_t)r0 * F + f];
        float a1 = dis_s[r1] * (float)base[(size_t)r1 * F + f];
        float a2 = dis_s[r2] * (float)base[(size_t)r2 * F + f];
        float a3 = dis_s[r3] * (float)base[(size_t)r3 * F + f];
        acc += (a0 + a1) + (a2 + a3);
    }
    for (; q < cnt; q++) {
        int r = list[off + q];
        acc += dis_s[r] * (float)base[(size_t)r * F + f];
    }
    float v = dj * acc + bias[f];
    if (RELU) v = fmaxf(v, 0.f);
    OUT[(size_t)j * 256 + outColOff + f] = (bf16_t)v;
}

// ---------------- FCN head ----------------
// split-K GEMM: partials[kb][32][256] = EMB(32x131072 bf16) @ W1(256x131072 fp32->bf16)^T, 256 K-chunks
__global__ __launch_bounds__(256) void k_fcn1(const bf16_t* __restrict__ EMB, const float* __restrict__ W1,
                                              float* __restrict__ partials) {
    int kb = blockIdx.x;
    int kbase = kb * 512;
    __shared__ bf16_t As[32][72];
    __shared__ bf16_t Bs[256][72];
    f32x4 acc[2][4] = {};
    int tid = threadIdx.x, wave = tid >> 6, lane = tid & 63;
    int wn = wave * 64;
    int fm = lane & 15, fq = lane >> 4;
    for (int ks = 0; ks < 512; ks += 64) {
        __syncthreads();
        {
            int row = tid >> 3, c = (tid & 7) * 8;
            *(uint4*)&As[row][c] = *(const uint4*)(EMB + (size_t)row * 131072 + kbase + ks + c);
        }
#pragma unroll
        for (int p = 0; p < 16; p++) {
            int g = p * 256 + tid;
            int row = g >> 4, c = (g & 15) * 4;
            float4 v = *(const float4*)(W1 + (size_t)row * 131072 + kbase + ks + c);
            bf16x4 o = {(bf16_t)v.x, (bf16_t)v.y, (bf16_t)v.z, (bf16_t)v.w};
            *(bf16x4*)&Bs[row][c] = o;
        }
        __syncthreads();
#pragma unroll
        for (int kk = 0; kk < 2; kk++) {
            bf16x8 a0 = *(const bf16x8*)&As[fm][kk * 32 + fq * 8];
            bf16x8 a1 = *(const bf16x8*)&As[16 + fm][kk * 32 + fq * 8];
#pragma unroll
            for (int j = 0; j < 4; j++) {
                bf16x8 bb = *(const bf16x8*)&Bs[wn + j * 16 + fm][kk * 32 + fq * 8];
                acc[0][j] = __builtin_amdgcn_mfma_f32_16x16x32_bf16(a0, bb, acc[0][j], 0, 0, 0);
                acc[1][j] = __builtin_amdgcn_mfma_f32_16x16x32_bf16(a1, bb, acc[1][j], 0, 0, 0);
            }
        }
    }
    float* P = partials + (size_t)kb * 8192;
#pragma unroll
    for (int i = 0; i < 2; i++)
#pragma unroll
        for (int j = 0; j < 4; j++)
#pragma unroll
            for (int r = 0; r < 4; r++)
                P[(size_t)(i * 16 + fq * 4 + r) * 256 + wn + j * 16 + fm] = acc[i][j][r];
}

// reduce 256 partials -> 8 (grid-wide, coalesced)
__global__ __launch_bounds__(256) void k_reduce(const float* __restrict__ partials, float* __restrict__ part2) {
    int kg = blockIdx.x >> 5, eb = blockIdx.x & 31;
    int e = eb * 256 + threadIdx.x;
    float s = 0;
#pragma unroll 8
    for (int i = 0; i < 32; i++) s += partials[(size_t)(kg * 32 + i) * 8192 + e];
    part2[(size_t)kg * 8192 + e] = s;
}

// final: h1 = leaky(sum part2 + b1); h2 = leaky(h1@W2^T+b2); out = h2@W3^T+b3
__global__ __launch_bounds__(256) void k_head(const float* __restrict__ part2, const float* __restrict__ b1,
                                              const float* __restrict__ W2, const float* __restrict__ b2,
                                              const float* __restrict__ W3, const float* __restrict__ b3,
                                              float* __restrict__ out) {
    __shared__ float h1s[32][256];
    __shared__ float h2s[32][32];
    int t = threadIdx.x;
    for (int i = 0; i < 32; i++) {
        int e = i * 256 + t;
        float s = 0;
#pragma unroll
        for (int kg = 0; kg < 8; kg++) s += part2[kg * 8192 + e];
        s += b1[t];
        h1s[i][t] = (s > 0.f) ? s : 0.2f * s;
    }
    __syncthreads();
    for (int p = 0; p < 4; p++) {
        int id = p * 256 + t, si = id >> 5, o2 = id & 31;
        float s = 0;
        for (int k = 0; k < 256; k++) s += h1s[si][k] * W2[o2 * 256 + k];
        s += b2[o2];
        h2s[si][o2] = (s > 0.f) ? s : 0.2f * s;
    }
    __syncthreads();
    if (t < 64) {
        int si = t >> 1, o3 = t & 1;
        float s = 0;
#pragma unroll
        for (int k = 0; k < 32; k++) s += h2s[si][k] * W3[o3 * 32 + k];
        out[si * 2 + o3] = s + b3[o3];
    }
}

// ---------------- launcher ----------------

extern "C" void kernel_launch(void* const* d_in, const int* in_sizes, int n_in,
                              void* d_out, int out_size, void* d_ws, size_t ws_size,
                              hipStream_t stream) {
    const float* x = (const float*)d_in[0];
    const float* t = (const float*)d_in[1];
    const float* gum = (const float*)d_in[2];
    const int* eidx = (const int*)d_in[3];
    const float* c1w = (const float*)d_in[4];
    const float* c1b = (const float*)d_in[5];
    const float* c2w = (const float*)d_in[6];
    const float* c2b = (const float*)d_in[7];
    const float* fcw = (const float*)d_in[8];
    const float* fcb = (const float*)d_in[9];
    const float* w1 = (const float*)d_in[10];
    const float* b1 = (const float*)d_in[11];
    const float* w2 = (const float*)d_in[12];
    const float* b2 = (const float*)d_in[13];
    const float* w3 = (const float*)d_in[14];
    const float* b3 = (const float*)d_in[15];
    float* out = (float*)d_out;
    (void)in_sizes; (void)n_in; (void)out_size; (void)ws_size;

    char* ws = (char*)d_ws;
    size_t off = 0;
    auto alloc = [&](size_t bytes) -> char* {
        char* p = ws + off;
        off += (bytes + 255) & ~size_t(255);
        return p;
    };
    // Aliased lifetimes (all launches sequential on one stream):
    //   xbf (until G1)  -> H (from G2/S4)
    //   XW1 (until S4)  -> EMB (from G4/S5)
    //   Z1T (until G2)  -> partials (from F1)
    bf16_t* xbf_H = (bf16_t*)alloc((size_t)32768 * 256 * 2);     // 16.8 MB
    bf16_t* c1wb = (bf16_t*)alloc((size_t)256 * 512 * 2);
    bf16_t* c2wb = (bf16_t*)alloc((size_t)128 * 256 * 2);
    float4* lsr = (float4*)alloc((size_t)kNTOT * 16);
    bf16_t* AT = (bf16_t*)alloc((size_t)kBZ * kN * kN * 2);      // 16.8 MB
    float* disd = (float*)alloc((size_t)kNTOT * 4);
    bf16_t* XW1_EMB = (bf16_t*)alloc((size_t)kNTOT * 256 * 2);   // 8.4 MB
    bf16_t* Z1T_part = (bf16_t*)alloc((size_t)kBZ * 256 * 512 * 2);  // 8.4 MB
    bf16_t* XW2 = (bf16_t*)alloc((size_t)32768 * 128 * 2);       // 8.4 MB
    bf16_t* Z2T = (bf16_t*)alloc((size_t)kBZ * 128 * 512 * 2);   // 4.2 MB
    int* counts = (int*)alloc((size_t)kNTOT * 4);
    int* offsets = (int*)alloc((size_t)kNTOT * 4);
    int* cursor = (int*)alloc((size_t)kNTOT * 4);
    float* diss = (float*)alloc((size_t)kNTOT * 4);
    int* list = (int*)alloc((size_t)kE * 4);
    float* part2 = (float*)alloc((size_t)8 * 8192 * 4);

    bf16_t* xbf = xbf_H;
    bf16_t* H = xbf_H;
    bf16_t* XW1 = XW1_EMB;
    bf16_t* EMB = XW1_EMB;
    bf16_t* Z1T = Z1T_part;
    float* partials = (float*)Z1T_part;

    k_zero<<<64, 256, 0, stream>>>(counts, kNTOT);
    k_cvt<<<8192, 256, 0, stream>>>(x, xbf, kNTOT * 512 / 4);
    k_cvt<<<128, 256, 0, stream>>>(c1w, c1wb, 256 * 512 / 4);
    k_cvt<<<32, 256, 0, stream>>>(c2w, c2wb, 128 * 256 / 4);
    k_lsr<<<4096, 256, 0, stream>>>(t, fcw, fcb, lsr);
    k_adj<<<dim3(8, 8, 32), 256, 0, stream>>>(gum, lsr, AT);
    k_degdis<<<4096, 256, 0, stream>>>(AT, disd);
    // XW1 = x @ conv1_w^T  (shared by dense + sparse paths)
    k_gemm<0><<<dim3(128, 2, 1), 256, 0, stream>>>(xbf, c1wb, XW1, 512, 512, 512, 256, 0, 0, 0, nullptr, nullptr);
    // sparse CSR build
    k_hist<<<2048, 256, 0, stream>>>(eidx + kE, counts);
    k_scan<<<1, 256, 0, stream>>>(counts, offsets, cursor, diss);
    k_fill<<<2048, 256, 0, stream>>>(eidx, eidx + kE, cursor, list);
    // dense layer 1
    k_scaleT<256><<<dim3(4, 8, 32), 256, 0, stream>>>(XW1, disd, Z1T);
    k_gemm<1><<<dim3(4, 2, 32), 256, 0, stream>>>(AT, Z1T, H, 512, 512, 512, 256,
                                                  (size_t)512 * 512, (size_t)256 * 512, (size_t)512 * 256, disd, c1b);
    // sparse layer 1 -> H rows 16384..
    k_sagg<256, true><<<16384, 256, 0, stream>>>(XW1, 0, list, offsets, counts, diss, c1b,
                                                 H + (size_t)16384 * 256, 0);
    // layer 2 matmul for both paths stacked
    k_gemm<0><<<dim3(256, 1, 1), 256, 0, stream>>>(H, c2wb, XW2, 256, 256, 256, 128, 0, 0, 0, nullptr, nullptr);
    // dense layer 2 -> EMB cols 0..127
    k_scaleT<128><<<dim3(2, 8, 32), 256, 0, stream>>>(XW2, disd, Z2T);
    k_gemm<2><<<dim3(4, 1, 32), 256, 0, stream>>>(AT, Z2T, EMB, 512, 512, 512, 256,
                                                  (size_t)512 * 512, (size_t)128 * 512, (size_t)512 * 256, disd, c2b);
    // sparse layer 2 -> EMB cols 128..255
    k_sagg<128, false><<<8192, 256, 0, stream>>>(XW2, 16384, list, offsets, counts, diss, c2b, EMB, 128);
    // FCN head
    k_fcn1<<<256, 256, 0, stream>>>(EMB, w1, partials);
    k_reduce<<<256, 256, 0, stream>>>(partials, part2);
    k_head<<<1, 256, 0, stream>>>(part2, b1, w2, b2, w3, b3, out);
}

// Round 3
// 521.668 us; speedup vs baseline: 1.1878x; 1.1878x over previous
//
#include <hip/hip_runtime.h>
#include <hip/hip_bf16.h>

typedef __bf16 bf16_t;
typedef __bf16 bf16x8 __attribute__((ext_vector_type(8)));
typedef __bf16 bf16x4 __attribute__((ext_vector_type(4)));
typedef float f32x4 __attribute__((ext_vector_type(4)));

constexpr int kN = 512;       // nodes per sample
constexpr int kBZ = 32;       // batch
constexpr int kTC = 256;
constexpr int kE = 524288;
constexpr int kNTOT = 16384;  // kBZ*kN

// ---------------- fused convert + zero ----------------
// ranges (in float4/int4 quads): x (2097152), c1w (32768), c2w (8192), zero counts (4096)
__global__ __launch_bounds__(256) void k_cvt3(const float* __restrict__ x, const float* __restrict__ c1w,
                                              const float* __restrict__ c2w, bf16_t* __restrict__ xb,
                                              bf16_t* __restrict__ c1b, bf16_t* __restrict__ c2b,
                                              int* __restrict__ counts) {
    int i = blockIdx.x * 256 + threadIdx.x;
    const int n0 = 2097152, n1 = n0 + 32768, n2 = n1 + 8192, n3 = n2 + 4096;
    if (i < n0) {
        float4 v = ((const float4*)x)[i];
        bf16x4 o = {(bf16_t)v.x, (bf16_t)v.y, (bf16_t)v.z, (bf16_t)v.w};
        ((bf16x4*)xb)[i] = o;
    } else if (i < n1) {
        int j = i - n0;
        float4 v = ((const float4*)c1w)[j];
        bf16x4 o = {(bf16_t)v.x, (bf16_t)v.y, (bf16_t)v.z, (bf16_t)v.w};
        ((bf16x4*)c1b)[j] = o;
    } else if (i < n2) {
        int j = i - n1;
        float4 v = ((const float4*)c2w)[j];
        bf16x4 o = {(bf16_t)v.x, (bf16_t)v.y, (bf16_t)v.z, (bf16_t)v.w};
        ((bf16x4*)c2b)[j] = o;
    } else if (i < n3) {
        int j = i - n2;
        ((int4*)counts)[j] = make_int4(0, 0, 0, 0);
    }
}

// P0=ls0+b0, P1=ls1+b1, Q0=lr0, Q1=lr1 per row (u = relu(t))
__global__ __launch_bounds__(256) void k_lsr(const float* __restrict__ tin, const float* __restrict__ fcw,
                                             const float* __restrict__ fcb, float4* __restrict__ lsr) {
    int row = blockIdx.x * 4 + (threadIdx.x >> 6);
    int lane = threadIdx.x & 63;
    const float* tr = tin + (size_t)row * kTC;
    float s0 = 0, s1 = 0, r0 = 0, r1 = 0;
    for (int k = lane; k < kTC; k += 64) {
        float u = fmaxf(tr[k], 0.f);
        s0 += u * fcw[k];
        s1 += u * fcw[512 + k];
        r0 += u * fcw[256 + k];
        r1 += u * fcw[768 + k];
    }
#pragma unroll
    for (int off = 32; off > 0; off >>= 1) {
        s0 += __shfl_down(s0, off); s1 += __shfl_down(s1, off);
        r0 += __shfl_down(r0, off); r1 += __shfl_down(r1, off);
    }
    if (lane == 0) lsr[row] = make_float4(s0 + fcb[0], s1 + fcb[1], r0, r1);
}

// Ah_T[s][j][i] = (argmax_k(lr[i,k]+ls[j,k]+b[k]+g[i,j,k]) == 0) + (i==j), bf16 {0,1,2}
__global__ __launch_bounds__(256) void k_adj(const float* __restrict__ gum, const float4* __restrict__ lsr,
                                             bf16_t* __restrict__ AT) {
    int s = blockIdx.z;
    int a0 = blockIdx.y * 64, b0 = blockIdx.x * 64;
    __shared__ bf16_t tile[64][72];
    int t = threadIdx.x;
    int lb = t & 63, ra = t >> 6;
    int b = b0 + lb;
    float4 pb = lsr[s * kN + b];
#pragma unroll 4
    for (int p = 0; p < 16; p++) {
        int a = a0 + p * 4 + ra;
        float4 qa = lsr[s * kN + a];
        const float* g = gum + ((((size_t)s * kN + a) * kN + b) << 1);
        float u0 = fmaxf(g[0], 1e-9f);
        float u1 = fmaxf(g[1], 1e-9f);
        float g0 = -__logf(-__logf(u0));
        float g1 = -__logf(-__logf(u1));
        float v = ((qa.z + pb.x + g0) >= (qa.w + pb.y + g1)) ? 1.f : 0.f;
        if (a == b) v += 1.f;
        tile[lb][p * 4 + ra] = (bf16_t)v;
    }
    __syncthreads();
    int rj = t >> 3, li = (t & 7) * 8;
#pragma unroll
    for (int p = 0; p < 2; p++) {
        int j = p * 32 + rj;
        *(bf16x8*)(AT + ((size_t)s * kN + b0 + j) * kN + a0 + li) = *(const bf16x8*)&tile[j][li];
    }
}

// dis_d[row] = rsqrt(row-sum of Ah_T)
__global__ __launch_bounds__(256) void k_degdis(const bf16_t* __restrict__ AT, float* __restrict__ dis) {
    int row = blockIdx.x * 4 + (threadIdx.x >> 6);
    int lane = threadIdx.x & 63;
    bf16x8 v = *(const bf16x8*)(AT + (size_t)row * kN + lane * 8);
    float s = 0;
#pragma unroll
    for (int i = 0; i < 8; i++) s += (float)v[i];
#pragma unroll
    for (int off = 32; off > 0; off >>= 1) s += __shfl_down(s, off);
    if (lane == 0) dis[row] = rsqrtf(s);
}

// ---------------- bf16 NT GEMM: C(MxN) = A(MxK) * B(NxK)^T, 128x128 tile, BK=64 ----------------
template <int MODE>
__global__ __launch_bounds__(256) void k_gemm(const bf16_t* __restrict__ A, const bf16_t* __restrict__ B,
                                              bf16_t* __restrict__ C, int K, int lda, int ldb, int ldc,
                                              size_t sA, size_t sB, size_t sC,
                                              const float* __restrict__ scale, const float* __restrict__ bias) {
    int m0 = blockIdx.x * 128, n0 = blockIdx.y * 128, s = blockIdx.z;
    A += sA * s; B += sB * s; C += sC * s;
    __shared__ bf16_t As[128][72], Bs[128][72];
    f32x4 acc[4][4] = {};
    int tid = threadIdx.x;
    int wave = tid >> 6, lane = tid & 63;
    int wm = (wave & 1) * 64, wn = (wave >> 1) * 64;
    int fm = lane & 15, fq = lane >> 4;
    int srow = tid >> 3, scol = (tid & 7) * 8;
    for (int kb = 0; kb < K; kb += 64) {
        __syncthreads();
#pragma unroll
        for (int p = 0; p < 4; p++) {
            int row = p * 32 + srow;
            *(uint4*)&As[row][scol] = *(const uint4*)(A + (size_t)(m0 + row) * lda + kb + scol);
            *(uint4*)&Bs[row][scol] = *(const uint4*)(B + (size_t)(n0 + row) * ldb + kb + scol);
        }
        __syncthreads();
#pragma unroll
        for (int kk = 0; kk < 2; kk++) {
            bf16x8 af[4], bfr[4];
#pragma unroll
            for (int i = 0; i < 4; i++) {
                af[i] = *(const bf16x8*)&As[wm + i * 16 + fm][kk * 32 + fq * 8];
                bfr[i] = *(const bf16x8*)&Bs[wn + i * 16 + fm][kk * 32 + fq * 8];
            }
#pragma unroll
            for (int i = 0; i < 4; i++)
#pragma unroll
                for (int j = 0; j < 4; j++)
                    acc[i][j] = __builtin_amdgcn_mfma_f32_16x16x32_bf16(af[i], bfr[j], acc[i][j], 0, 0, 0);
        }
    }
#pragma unroll
    for (int i = 0; i < 4; i++) {
#pragma unroll
        for (int r = 0; r < 4; r++) {
            int row = wm + i * 16 + fq * 4 + r;
            float sc = 1.f;
            if constexpr (MODE != 0) sc = scale[(size_t)s * kN + m0 + row];
#pragma unroll
            for (int j = 0; j < 4; j++) {
                int col = n0 + wn + j * 16 + fm;
                float v = acc[i][j][r];
                if constexpr (MODE == 1) v = fmaxf(sc * v + bias[col], 0.f);
                if constexpr (MODE == 2) v = sc * v + bias[col];
                C[(size_t)(m0 + row) * ldc + col] = (bf16_t)v;
            }
        }
    }
}

// ZT[s][f][i] = bf16(dis[s,i] * XW[s*512+i, f]) — scale + transpose via LDS tile
template <int F>
__global__ __launch_bounds__(256) void k_scaleT(const bf16_t* __restrict__ XW, const float* __restrict__ dis,
                                                bf16_t* __restrict__ ZT) {
    int s = blockIdx.z, i0 = blockIdx.y * 64, f0 = blockIdx.x * 64;
    __shared__ bf16_t tile[64][72];
    int t = threadIdx.x;
    int gi = t >> 3, gc = (t & 7) * 8;
#pragma unroll
    for (int p = 0; p < 2; p++) {
        int i = p * 32 + gi;
        bf16x8 v = *(const bf16x8*)(XW + (size_t)(s * kN + i0 + i) * F + f0 + gc);
        float d = dis[s * kN + i0 + i];
#pragma unroll
        for (int q = 0; q < 8; q++) tile[gc + q][i] = (bf16_t)(d * (float)v[q]);
    }
    __syncthreads();
#pragma unroll
    for (int p = 0; p < 2; p++) {
        int f = p * 32 + gi;
        *(bf16x8*)(ZT + (size_t)(s * F + f0 + f) * kN + i0 + gc) = *(const bf16x8*)&tile[f][gc];
    }
}

// ---------------- sparse path ----------------

__global__ __launch_bounds__(256) void k_hist(const int* __restrict__ col, int* __restrict__ counts) {
    int e = blockIdx.x * 256 + threadIdx.x;
    if (e < kE) atomicAdd(&counts[col[e]], 1);
}

// single block; single 64KB LDS array, in-place counts->offsets; all global R/W coalesced
__global__ __launch_bounds__(256) void k_scan(const int* __restrict__ counts, int* __restrict__ offsets,
                                              int* __restrict__ cursor, float* __restrict__ dis_s) {
    __shared__ int ldc_[16384];
    __shared__ int sums[256];
    int t = threadIdx.x;
    for (int i = 0; i < 64; i++) {
        int g = i * 256 + t;
        int c = counts[g];
        ldc_[g] = c;
        dis_s[g] = rsqrtf((float)(c + 1));  // deg includes self loop
    }
    __syncthreads();
    int s = 0;
    for (int i = 0; i < 64; i++) s += ldc_[t * 64 + i];
    sums[t] = s;
    __syncthreads();
    for (int off = 1; off < 256; off <<= 1) {
        int y = (t >= off) ? sums[t - off] : 0;
        __syncthreads();
        sums[t] += y;
        __syncthreads();
    }
    int run = sums[t] - s;  // exclusive prefix
    for (int i = 0; i < 64; i++) {
        int j = t * 64 + i;
        int c = ldc_[j];
        ldc_[j] = run;  // in-place: counts -> offsets
        run += c;
    }
    __syncthreads();
    for (int i = 0; i < 64; i++) {
        int g = i * 256 + t;
        int o = ldc_[g];
        offsets[g] = o;
        cursor[g] = o;
    }
}

__global__ __launch_bounds__(256) void k_fill(const int* __restrict__ row, const int* __restrict__ col,
                                              int* __restrict__ cursor, int* __restrict__ list) {
    int e = blockIdx.x * 256 + threadIdx.x;
    if (e < kE) {
        int p = atomicAdd(&cursor[col[e]], 1);
        list[p] = row[e];
    }
}

// out[j,f8..f8+7] via bf16x8 gathers; OUT row j, ld 256
template <int F, bool RELU>
__global__ __launch_bounds__(256) void k_sagg(const bf16_t* __restrict__ XW, int rowOffIn,
                                              const int* __restrict__ list, const int* __restrict__ offsets,
                                              const int* __restrict__ counts, const float* __restrict__ dis_s,
                                              const float* __restrict__ bias, bf16_t* __restrict__ OUT,
                                              int outColOff) {
    constexpr int TPR = F / 8;        // threads per row
    constexpr int RPB = 256 / TPR;    // rows per block
    int j = blockIdx.x * RPB + threadIdx.x / TPR;
    int f8 = (threadIdx.x % TPR) * 8;
    float dj = dis_s[j];
    const bf16_t* base = XW + (size_t)rowOffIn * F;
    float acc[8];
    {
        bf16x8 v = *(const bf16x8*)(base + (size_t)j * F + f8);
#pragma unroll
        for (int q = 0; q < 8; q++) acc[q] = dj * (float)v[q];
    }
    int off = offsets[j], cnt = counts[j];
    int e = 0;
    for (; e + 4 <= cnt; e += 4) {
        int r0 = list[off + e], r1 = list[off + e + 1], r2 = list[off + e + 2], r3 = list[off + e + 3];
        float d0 = dis_s[r0], d1 = dis_s[r1], d2 = dis_s[r2], d3 = dis_s[r3];
        bf16x8 v0 = *(const bf16x8*)(base + (size_t)r0 * F + f8);
        bf16x8 v1 = *(const bf16x8*)(base + (size_t)r1 * F + f8);
        bf16x8 v2 = *(const bf16x8*)(base + (size_t)r2 * F + f8);
        bf16x8 v3 = *(const bf16x8*)(base + (size_t)r3 * F + f8);
#pragma unroll
        for (int q = 0; q < 8; q++)
            acc[q] += (d0 * (float)v0[q] + d1 * (float)v1[q]) + (d2 * (float)v2[q] + d3 * (float)v3[q]);
    }
    for (; e < cnt; e++) {
        int r = list[off + e];
        float d = dis_s[r];
        bf16x8 v = *(const bf16x8*)(base + (size_t)r * F + f8);
#pragma unroll
        for (int q = 0; q < 8; q++) acc[q] += d * (float)v[q];
    }
    bf16x8 o;
#pragma unroll
    for (int q = 0; q < 8; q++) {
        float v = dj * acc[q] + bias[f8 + q];
        if (RELU) v = fmaxf(v, 0.f);
        o[q] = (bf16_t)v;
    }
    *(bf16x8*)(OUT + (size_t)j * 256 + outColOff + f8) = o;
}

// ---------------- FCN head ----------------
// register-direct split-K MFMA: 512 blocks, block b covers K chunk [b*256, b*256+256).
// Each wave covers 64 of the 256 output cols (4 n-tiles), both 16-row m-tiles.
__global__ __launch_bounds__(256) void k_fcn1(const bf16_t* __restrict__ EMB, const float* __restrict__ W1,
                                              float* __restrict__ partials) {
    int tid = threadIdx.x, wave = tid >> 6, lane = tid & 63;
    int fm = lane & 15, fq = lane >> 4;
    int kb0 = blockIdx.x * 256;
    f32x4 acc[2][4] = {};
#pragma unroll 2
    for (int ks = 0; ks < 256; ks += 32) {
        int k = kb0 + ks + fq * 8;
        bf16x8 a0 = *(const bf16x8*)(EMB + (size_t)fm * 131072 + k);
        bf16x8 a1 = *(const bf16x8*)(EMB + (size_t)(16 + fm) * 131072 + k);
        bf16x8 bfr[4];
#pragma unroll
        for (int j = 0; j < 4; j++) {
            int n = wave * 64 + j * 16 + fm;
            const float* p = W1 + (size_t)n * 131072 + k;
            float4 lo = *(const float4*)p;
            float4 hi = *(const float4*)(p + 4);
            bf16x8 b = {(bf16_t)lo.x, (bf16_t)lo.y, (bf16_t)lo.z, (bf16_t)lo.w,
                        (bf16_t)hi.x, (bf16_t)hi.y, (bf16_t)hi.z, (bf16_t)hi.w};
            bfr[j] = b;
        }
#pragma unroll
        for (int j = 0; j < 4; j++) {
            acc[0][j] = __builtin_amdgcn_mfma_f32_16x16x32_bf16(a0, bfr[j], acc[0][j], 0, 0, 0);
            acc[1][j] = __builtin_amdgcn_mfma_f32_16x16x32_bf16(a1, bfr[j], acc[1][j], 0, 0, 0);
        }
    }
    float* P = partials + (size_t)blockIdx.x * 8192;
#pragma unroll
    for (int i = 0; i < 2; i++)
#pragma unroll
        for (int j = 0; j < 4; j++)
#pragma unroll
            for (int r = 0; r < 4; r++)
                P[(size_t)(i * 16 + fq * 4 + r) * 256 + wave * 64 + j * 16 + fm] = acc[i][j][r];
}

// reduce 512 partials -> 8 (grid-wide, coalesced)
__global__ __launch_bounds__(256) void k_reduce(const float* __restrict__ partials, float* __restrict__ part2) {
    int kg = blockIdx.x >> 5, eb = blockIdx.x & 31;
    int e = eb * 256 + threadIdx.x;
    float s = 0;
#pragma unroll 8
    for (int i = 0; i < 64; i++) s += partials[(size_t)(kg * 64 + i) * 8192 + e];
    part2[(size_t)kg * 8192 + e] = s;
}

// final: h1 = leaky(sum part2 + b1); h2 = leaky(h1@W2^T+b2); out = h2@W3^T+b3
__global__ __launch_bounds__(256) void k_head(const float* __restrict__ part2, const float* __restrict__ b1,
                                              const float* __restrict__ W2, const float* __restrict__ b2,
                                              const float* __restrict__ W3, const float* __restrict__ b3,
                                              float* __restrict__ out) {
    __shared__ float h1s[32][256];
    __shared__ float h2s[32][32];
    int t = threadIdx.x;
    for (int i = 0; i < 32; i++) {
        int e = i * 256 + t;
        float s = 0;
#pragma unroll
        for (int kg = 0; kg < 8; kg++) s += part2[kg * 8192 + e];
        s += b1[t];
        h1s[i][t] = (s > 0.f) ? s : 0.2f * s;
    }
    __syncthreads();
    for (int p = 0; p < 4; p++) {
        int id = p * 256 + t, si = id >> 5, o2 = id & 31;
        float s = 0;
        for (int k = 0; k < 256; k++) s += h1s[si][k] * W2[o2 * 256 + k];
        s += b2[o2];
        h2s[si][o2] = (s > 0.f) ? s : 0.2f * s;
    }
    __syncthreads();
    if (t < 64) {
        int si = t >> 1, o3 = t & 1;
        float s = 0;
#pragma unroll
        for (int k = 0; k < 32; k++) s += h2s[si][k] * W3[o3 * 32 + k];
        out[si * 2 + o3] = s + b3[o3];
    }
}

// ---------------- launcher ----------------

extern "C" void kernel_launch(void* const* d_in, const int* in_sizes, int n_in,
                              void* d_out, int out_size, void* d_ws, size_t ws_size,
                              hipStream_t stream) {
    const float* x = (const float*)d_in[0];
    const float* t = (const float*)d_in[1];
    const float* gum = (const float*)d_in[2];
    const int* eidx = (const int*)d_in[3];
    const float* c1w = (const float*)d_in[4];
    const float* c1b = (const float*)d_in[5];
    const float* c2w = (const float*)d_in[6];
    const float* c2b = (const float*)d_in[7];
    const float* fcw = (const float*)d_in[8];
    const float* fcb = (const float*)d_in[9];
    const float* w1 = (const float*)d_in[10];
    const float* b1 = (const float*)d_in[11];
    const float* w2 = (const float*)d_in[12];
    const float* b2 = (const float*)d_in[13];
    const float* w3 = (const float*)d_in[14];
    const float* b3 = (const float*)d_in[15];
    float* out = (float*)d_out;
    (void)in_sizes; (void)n_in; (void)out_size; (void)ws_size;

    char* ws = (char*)d_ws;
    size_t off = 0;
    auto alloc = [&](size_t bytes) -> char* {
        char* p = ws + off;
        off += (bytes + 255) & ~size_t(255);
        return p;
    };
    // Aliased lifetimes (all launches sequential on one stream):
    //   xbf (until G1)  -> H (from G2/S4)
    //   XW1 (until S4)  -> EMB (from G4/S5)
    //   AT  (until G5)  -> partials (from F1; 512*8192*4 = 16.8 MB = AT size exactly)
    bf16_t* xbf_H = (bf16_t*)alloc((size_t)32768 * 256 * 2);         // 16.8 MB
    bf16_t* c1wb = (bf16_t*)alloc((size_t)256 * 512 * 2);
    bf16_t* c2wb = (bf16_t*)alloc((size_t)128 * 256 * 2);
    float4* lsr = (float4*)alloc((size_t)kNTOT * 16);
    bf16_t* AT = (bf16_t*)alloc((size_t)kBZ * kN * kN * 2);          // 16.8 MB
    float* disd = (float*)alloc((size_t)kNTOT * 4);
    bf16_t* XW1_EMB = (bf16_t*)alloc((size_t)kNTOT * 256 * 2);       // 8.4 MB
    bf16_t* Z1T = (bf16_t*)alloc((size_t)kBZ * 256 * 512 * 2);       // 8.4 MB
    bf16_t* XW2 = (bf16_t*)alloc((size_t)32768 * 128 * 2);           // 8.4 MB
    bf16_t* Z2T = (bf16_t*)alloc((size_t)kBZ * 128 * 512 * 2);       // 4.2 MB
    int* counts = (int*)alloc((size_t)kNTOT * 4);
    int* offsets = (int*)alloc((size_t)kNTOT * 4);
    int* cursor = (int*)alloc((size_t)kNTOT * 4);
    float* diss = (float*)alloc((size_t)kNTOT * 4);
    int* list = (int*)alloc((size_t)kE * 4);
    float* part2 = (float*)alloc((size_t)8 * 8192 * 4);

    bf16_t* xbf = xbf_H;
    bf16_t* H = xbf_H;
    bf16_t* XW1 = XW1_EMB;
    bf16_t* EMB = XW1_EMB;
    float* partials = (float*)AT;

    k_cvt3<<<8368, 256, 0, stream>>>(x, c1w, c2w, xbf, c1wb, c2wb, counts);
    k_lsr<<<4096, 256, 0, stream>>>(t, fcw, fcb, lsr);
    k_adj<<<dim3(8, 8, 32), 256, 0, stream>>>(gum, lsr, AT);
    k_degdis<<<4096, 256, 0, stream>>>(AT, disd);
    // XW1 = x @ conv1_w^T  (shared by dense + sparse paths)
    k_gemm<0><<<dim3(128, 2, 1), 256, 0, stream>>>(xbf, c1wb, XW1, 512, 512, 512, 256, 0, 0, 0, nullptr, nullptr);
    // sparse CSR build
    k_hist<<<2048, 256, 0, stream>>>(eidx + kE, counts);
    k_scan<<<1, 256, 0, stream>>>(counts, offsets, cursor, diss);
    k_fill<<<2048, 256, 0, stream>>>(eidx, eidx + kE, cursor, list);
    // dense layer 1
    k_scaleT<256><<<dim3(4, 8, 32), 256, 0, stream>>>(XW1, disd, Z1T);
    k_gemm<1><<<dim3(4, 2, 32), 256, 0, stream>>>(AT, Z1T, H, 512, 512, 512, 256,
                                                  (size_t)512 * 512, (size_t)256 * 512, (size_t)512 * 256, disd, c1b);
    // sparse layer 1 -> H rows 16384..  (RPB=8 -> 2048 blocks)
    k_sagg<256, true><<<2048, 256, 0, stream>>>(XW1, 0, list, offsets, counts, diss, c1b,
                                                H + (size_t)16384 * 256, 0);
    // layer 2 matmul for both paths stacked
    k_gemm<0><<<dim3(256, 1, 1), 256, 0, stream>>>(H, c2wb, XW2, 256, 256, 256, 128, 0, 0, 0, nullptr, nullptr);
    // dense layer 2 -> EMB cols 0..127
    k_scaleT<128><<<dim3(2, 8, 32), 256, 0, stream>>>(XW2, disd, Z2T);
    k_gemm<2><<<dim3(4, 1, 32), 256, 0, stream>>>(AT, Z2T, EMB, 512, 512, 512, 256,
                                                  (size_t)512 * 512, (size_t)128 * 512, (size_t)512 * 256, disd, c2b);
    // sparse layer 2 -> EMB cols 128..255  (RPB=16 -> 1024 blocks for 16384 rows)
    k_sagg<128, false><<<1024, 256, 0, stream>>>(XW2, 16384, list, offsets, counts, diss, c2b, EMB, 128);
    // FCN head
    k_fcn1<<<512, 256, 0, stream>>>(EMB, w1, partials);
    k_reduce<<<256, 256, 0, stream>>>(partials, part2);
    k_head<<<1, 256, 0, stream>>>(part2, b1, w2, b2, w3, b3, out);
}

// Round 4
// 517.267 us; speedup vs baseline: 1.1980x; 1.0085x over previous
//
#include <hip/hip_runtime.h>
#include <hip/hip_bf16.h>

typedef __bf16 bf16_t;
typedef __bf16 bf16x8 __attribute__((ext_vector_type(8)));
typedef __bf16 bf16x4 __attribute__((ext_vector_type(4)));
typedef float f32x4 __attribute__((ext_vector_type(4)));

constexpr int kN = 512;       // nodes per sample
constexpr int kBZ = 32;       // batch
constexpr int kTC = 256;
constexpr int kE = 524288;
constexpr int kNTOT = 16384;  // kBZ*kN

// ---------------- weight convert + zero-init ----------------
// quads: c1w (32768), c2w (8192), counts zero (4096 int4), degsum zero (4096 float4)
__global__ __launch_bounds__(256) void k_cvt3(const float* __restrict__ c1w, const float* __restrict__ c2w,
                                              bf16_t* __restrict__ c1b, bf16_t* __restrict__ c2b,
                                              int* __restrict__ counts, float* __restrict__ degsum) {
    int i = blockIdx.x * 256 + threadIdx.x;
    const int n0 = 32768, n1 = n0 + 8192, n2 = n1 + 4096, n3 = n2 + 4096;
    if (i < n0) {
        float4 v = ((const float4*)c1w)[i];
        bf16x4 o = {(bf16_t)v.x, (bf16_t)v.y, (bf16_t)v.z, (bf16_t)v.w};
        ((bf16x4*)c1b)[i] = o;
    } else if (i < n1) {
        int j = i - n0;
        float4 v = ((const float4*)c2w)[j];
        bf16x4 o = {(bf16_t)v.x, (bf16_t)v.y, (bf16_t)v.z, (bf16_t)v.w};
        ((bf16x4*)c2b)[j] = o;
    } else if (i < n2) {
        ((int4*)counts)[i - n1] = make_int4(0, 0, 0, 0);
    } else if (i < n3) {
        ((float4*)degsum)[i - n2] = make_float4(0.f, 0.f, 0.f, 0.f);
    }
}

// P0=ls0+b0, P1=ls1+b1, Q0=lr0, Q1=lr1 per row (u = relu(t))
__global__ __launch_bounds__(256) void k_lsr(const float* __restrict__ tin, const float* __restrict__ fcw,
                                             const float* __restrict__ fcb, float4* __restrict__ lsr) {
    int row = blockIdx.x * 4 + (threadIdx.x >> 6);
    int lane = threadIdx.x & 63;
    const float* tr = tin + (size_t)row * kTC;
    float s0 = 0, s1 = 0, r0 = 0, r1 = 0;
    for (int k = lane; k < kTC; k += 64) {
        float u = fmaxf(tr[k], 0.f);
        s0 += u * fcw[k];
        s1 += u * fcw[512 + k];
        r0 += u * fcw[256 + k];
        r1 += u * fcw[768 + k];
    }
#pragma unroll
    for (int off = 32; off > 0; off >>= 1) {
        s0 += __shfl_down(s0, off); s1 += __shfl_down(s1, off);
        r0 += __shfl_down(r0, off); r1 += __shfl_down(r1, off);
    }
    if (lane == 0) lsr[row] = make_float4(s0 + fcb[0], s1 + fcb[1], r0, r1);
}

// Ah_T[s][j][i] = (argmax==0) + (i==j); also accumulates degsum[j] = row-sum via atomics
__global__ __launch_bounds__(256) void k_adj(const float* __restrict__ gum, const float4* __restrict__ lsr,
                                             bf16_t* __restrict__ AT, float* __restrict__ degsum) {
    int s = blockIdx.z;
    int a0 = blockIdx.y * 64, b0 = blockIdx.x * 64;
    __shared__ bf16_t tile[64][72];
    int t = threadIdx.x;
    int lb = t & 63, ra = t >> 6;
    int b = b0 + lb;
    float4 pb = lsr[s * kN + b];
#pragma unroll 4
    for (int p = 0; p < 16; p++) {
        int a = a0 + p * 4 + ra;
        float4 qa = lsr[s * kN + a];
        const float* g = gum + ((((size_t)s * kN + a) * kN + b) << 1);
        float u0 = fmaxf(g[0], 1e-9f);
        float u1 = fmaxf(g[1], 1e-9f);
        float g0 = -__logf(-__logf(u0));
        float g1 = -__logf(-__logf(u1));
        float v = ((qa.z + pb.x + g0) >= (qa.w + pb.y + g1)) ? 1.f : 0.f;
        if (a == b) v += 1.f;
        tile[lb][p * 4 + ra] = (bf16_t)v;
    }
    __syncthreads();
    int rj = t >> 3, li = (t & 7) * 8;
#pragma unroll
    for (int p = 0; p < 2; p++) {
        int j = p * 32 + rj;
        bf16x8 v = *(const bf16x8*)&tile[j][li];
        *(bf16x8*)(AT + ((size_t)s * kN + b0 + j) * kN + a0 + li) = v;
        float ps = 0;
#pragma unroll
        for (int q = 0; q < 8; q++) ps += (float)v[q];
        ps += __shfl_down(ps, 4);
        ps += __shfl_down(ps, 2);
        ps += __shfl_down(ps, 1);
        if ((t & 7) == 0) atomicAdd(degsum + s * kN + b0 + j, ps);
    }
}

// ---------------- bf16 NT GEMM: C(MxN) = A(MxK) * B(NxK)^T, 128x128 tile, BK=64 ----------------
// MODE 1: C = relu(rsqrt(deg[row])*acc + bias[col]). MODE 2: same, no relu.
template <int MODE>
__global__ __launch_bounds__(256) void k_gemm(const bf16_t* __restrict__ A, const bf16_t* __restrict__ B,
                                              bf16_t* __restrict__ C, int K, int lda, int ldb, int ldc,
                                              size_t sA, size_t sB, size_t sC,
                                              const float* __restrict__ degsum, const float* __restrict__ bias) {
    int m0 = blockIdx.x * 128, n0 = blockIdx.y * 128, s = blockIdx.z;
    A += sA * s; B += sB * s; C += sC * s;
    __shared__ bf16_t As[128][72], Bs[128][72];
    f32x4 acc[4][4] = {};
    int tid = threadIdx.x;
    int wave = tid >> 6, lane = tid & 63;
    int wm = (wave & 1) * 64, wn = (wave >> 1) * 64;
    int fm = lane & 15, fq = lane >> 4;
    int srow = tid >> 3, scol = (tid & 7) * 8;
    for (int kb = 0; kb < K; kb += 64) {
        __syncthreads();
#pragma unroll
        for (int p = 0; p < 4; p++) {
            int row = p * 32 + srow;
            *(uint4*)&As[row][scol] = *(const uint4*)(A + (size_t)(m0 + row) * lda + kb + scol);
            *(uint4*)&Bs[row][scol] = *(const uint4*)(B + (size_t)(n0 + row) * ldb + kb + scol);
        }
        __syncthreads();
#pragma unroll
        for (int kk = 0; kk < 2; kk++) {
            bf16x8 af[4], bfr[4];
#pragma unroll
            for (int i = 0; i < 4; i++) {
                af[i] = *(const bf16x8*)&As[wm + i * 16 + fm][kk * 32 + fq * 8];
                bfr[i] = *(const bf16x8*)&Bs[wn + i * 16 + fm][kk * 32 + fq * 8];
            }
#pragma unroll
            for (int i = 0; i < 4; i++)
#pragma unroll
                for (int j = 0; j < 4; j++)
                    acc[i][j] = __builtin_amdgcn_mfma_f32_16x16x32_bf16(af[i], bfr[j], acc[i][j], 0, 0, 0);
        }
    }
#pragma unroll
    for (int i = 0; i < 4; i++) {
#pragma unroll
        for (int r = 0; r < 4; r++) {
            int row = wm + i * 16 + fq * 4 + r;
            float sc = rsqrtf(degsum[(size_t)s * kN + m0 + row]);
#pragma unroll
            for (int j = 0; j < 4; j++) {
                int col = n0 + wn + j * 16 + fm;
                float v = sc * acc[i][j][r] + bias[col];
                if constexpr (MODE == 1) v = fmaxf(v, 0.f);
                C[(size_t)(m0 + row) * ldc + col] = (bf16_t)v;
            }
        }
    }
}

// ---- fused GEMM variants producing XW (plain) + ZT (scaled transpose) ----
// AF32: A operand is fp32, converted during staging. F = output cols (ld of XW).
// ZT[s][f][i] = rsqrt(deg[row]) * XW[row][f], row = s*512+i. DENSE_ROWS limits ZT writes.
template <bool AF32, int F, int DENSE_ROWS>
__global__ __launch_bounds__(256) void k_gemmT(const void* __restrict__ Ap, const bf16_t* __restrict__ B,
                                               bf16_t* __restrict__ XW, bf16_t* __restrict__ ZT, int K,
                                               const float* __restrict__ degsum) {
    int m0 = blockIdx.x * 128, n0 = blockIdx.y * 128;
    __shared__ __align__(16) bf16_t smem[2 * 128 * 72];  // As | Bs; reused as T[128][136]
    bf16_t* AsBase = smem;
    bf16_t* BsBase = smem + 128 * 72;
    f32x4 acc[4][4] = {};
    int tid = threadIdx.x;
    int wave = tid >> 6, lane = tid & 63;
    int wm = (wave & 1) * 64, wn = (wave >> 1) * 64;
    int fm = lane & 15, fq = lane >> 4;
    int srow = tid >> 3, scol = (tid & 7) * 8;
    for (int kb = 0; kb < K; kb += 64) {
        __syncthreads();
#pragma unroll
        for (int p = 0; p < 4; p++) {
            int row = p * 32 + srow;
            if constexpr (AF32) {
                const float* ap = (const float*)Ap + (size_t)(m0 + row) * K + kb + scol;
                float4 lo = *(const float4*)ap;
                float4 hi = *(const float4*)(ap + 4);
                bf16x8 o = {(bf16_t)lo.x, (bf16_t)lo.y, (bf16_t)lo.z, (bf16_t)lo.w,
                            (bf16_t)hi.x, (bf16_t)hi.y, (bf16_t)hi.z, (bf16_t)hi.w};
                *(bf16x8*)&AsBase[row * 72 + scol] = o;
            } else {
                *(uint4*)&AsBase[row * 72 + scol] =
                    *(const uint4*)((const bf16_t*)Ap + (size_t)(m0 + row) * K + kb + scol);
            }
            *(uint4*)&BsBase[row * 72 + scol] = *(const uint4*)(B + (size_t)(n0 + row) * K + kb + scol);
        }
        __syncthreads();
#pragma unroll
        for (int kk = 0; kk < 2; kk++) {
            bf16x8 af[4], bfr[4];
#pragma unroll
            for (int i = 0; i < 4; i++) {
                af[i] = *(const bf16x8*)&AsBase[(wm + i * 16 + fm) * 72 + kk * 32 + fq * 8];
                bfr[i] = *(const bf16x8*)&BsBase[(wn + i * 16 + fm) * 72 + kk * 32 + fq * 8];
            }
#pragma unroll
            for (int i = 0; i < 4; i++)
#pragma unroll
                for (int j = 0; j < 4; j++)
                    acc[i][j] = __builtin_amdgcn_mfma_f32_16x16x32_bf16(af[i], bfr[j], acc[i][j], 0, 0, 0);
        }
    }
    // write XW (unscaled) + stage scaled values into LDS transposed
    bool doT = (m0 < DENSE_ROWS);
    __syncthreads();  // all ds_reads of the K-loop complete before LDS reuse
#pragma unroll
    for (int i = 0; i < 4; i++) {
#pragma unroll
        for (int r = 0; r < 4; r++) {
            int row = wm + i * 16 + fq * 4 + r;
            float sc = doT ? rsqrtf(degsum[m0 + row]) : 0.f;
#pragma unroll
            for (int j = 0; j < 4; j++) {
                int col = wn + j * 16 + fm;
                float v = acc[i][j][r];
                XW[(size_t)(m0 + row) * F + n0 + col] = (bf16_t)v;
                if (doT) smem[col * 136 + row] = (bf16_t)(sc * v);
            }
        }
    }
    if (doT) {
        __syncthreads();
        int fr = tid >> 1, hi = (tid & 1) * 64;
        bf16_t* zrow = ZT + ((size_t)(m0 >> 9) * F + n0 + fr) * kN + (m0 & 511) + hi;
#pragma unroll
        for (int q = 0; q < 8; q++)
            *(bf16x8*)(zrow + q * 8) = *(const bf16x8*)&smem[fr * 136 + hi + q * 8];
    }
}

// ---------------- sparse path ----------------

__global__ __launch_bounds__(256) void k_hist(const int* __restrict__ col, int* __restrict__ counts) {
    int e = blockIdx.x * 256 + threadIdx.x;
    if (e < kE) atomicAdd(&counts[col[e]], 1);
}

// single block; padded LDS indexing (j + j/32) to avoid 64-way bank conflicts
__global__ __launch_bounds__(256) void k_scan(const int* __restrict__ counts, int* __restrict__ offsets,
                                              int* __restrict__ cursor, float* __restrict__ dis_s) {
    __shared__ int ldc_[16896];
    __shared__ int sums[256];
    int t = threadIdx.x;
#define IDX(j) ((j) + ((j) >> 5))
    for (int i = 0; i < 64; i++) {
        int g = i * 256 + t;
        int c = counts[g];
        ldc_[IDX(g)] = c;
        dis_s[g] = rsqrtf((float)(c + 1));  // deg includes self loop
    }
    __syncthreads();
    int s = 0;
    for (int i = 0; i < 64; i++) s += ldc_[IDX(t * 64 + i)];
    sums[t] = s;
    __syncthreads();
    for (int off = 1; off < 256; off <<= 1) {
        int y = (t >= off) ? sums[t - off] : 0;
        __syncthreads();
        sums[t] += y;
        __syncthreads();
    }
    int run = sums[t] - s;  // exclusive prefix
    for (int i = 0; i < 64; i++) {
        int j = t * 64 + i;
        int c = ldc_[IDX(j)];
        ldc_[IDX(j)] = run;
        run += c;
    }
    __syncthreads();
    for (int i = 0; i < 64; i++) {
        int g = i * 256 + t;
        int o = ldc_[IDX(g)];
        offsets[g] = o;
        cursor[g] = o;
    }
#undef IDX
}

__global__ __launch_bounds__(256) void k_fill(const int* __restrict__ row, const int* __restrict__ col,
                                              int* __restrict__ cursor, int* __restrict__ list) {
    int e = blockIdx.x * 256 + threadIdx.x;
    if (e < kE) {
        int p = atomicAdd(&cursor[col[e]], 1);
        list[p] = row[e];
    }
}

// out[j,f8..f8+7] via bf16x8 gathers; OUT row j, ld 256
template <int F, bool RELU>
__global__ __launch_bounds__(256) void k_sagg(const bf16_t* __restrict__ XW, int rowOffIn,
                                              const int* __restrict__ list, const int* __restrict__ offsets,
                                              const int* __restrict__ counts, const float* __restrict__ dis_s,
                                              const float* __restrict__ bias, bf16_t* __restrict__ OUT,
                                              int outColOff) {
    constexpr int TPR = F / 8;        // threads per row
    constexpr int RPB = 256 / TPR;    // rows per block
    int j = blockIdx.x * RPB + threadIdx.x / TPR;
    int f8 = (threadIdx.x % TPR) * 8;
    float dj = dis_s[j];
    const bf16_t* base = XW + (size_t)rowOffIn * F;
    float acc[8];
    {
        bf16x8 v = *(const bf16x8*)(base + (size_t)j * F + f8);
#pragma unroll
        for (int q = 0; q < 8; q++) acc[q] = dj * (float)v[q];
    }
    int off = offsets[j], cnt = counts[j];
    int e = 0;
    for (; e + 4 <= cnt; e += 4) {
        int r0 = list[off + e], r1 = list[off + e + 1], r2 = list[off + e + 2], r3 = list[off + e + 3];
        float d0 = dis_s[r0], d1 = dis_s[r1], d2 = dis_s[r2], d3 = dis_s[r3];
        bf16x8 v0 = *(const bf16x8*)(base + (size_t)r0 * F + f8);
        bf16x8 v1 = *(const bf16x8*)(base + (size_t)r1 * F + f8);
        bf16x8 v2 = *(const bf16x8*)(base + (size_t)r2 * F + f8);
        bf16x8 v3 = *(const bf16x8*)(base + (size_t)r3 * F + f8);
#pragma unroll
        for (int q = 0; q < 8; q++)
            acc[q] += (d0 * (float)v0[q] + d1 * (float)v1[q]) + (d2 * (float)v2[q] + d3 * (float)v3[q]);
    }
    for (; e < cnt; e++) {
        int r = list[off + e];
        float d = dis_s[r];
        bf16x8 v = *(const bf16x8*)(base + (size_t)r * F + f8);
#pragma unroll
        for (int q = 0; q < 8; q++) acc[q] += d * (float)v[q];
    }
    bf16x8 o;
#pragma unroll
    for (int q = 0; q < 8; q++) {
        float v = dj * acc[q] + bias[f8 + q];
        if (RELU) v = fmaxf(v, 0.f);
        o[q] = (bf16_t)v;
    }
    *(bf16x8*)(OUT + (size_t)j * 256 + outColOff + f8) = o;
}

// ---------------- FCN head ----------------
// register-direct split-K MFMA: 1024 blocks, block b covers K chunk [b*128, b*128+128).
__global__ __launch_bounds__(256) void k_fcn1(const bf16_t* __restrict__ EMB, const float* __restrict__ W1,
                                              float* __restrict__ partials) {
    int tid = threadIdx.x, wave = tid >> 6, lane = tid & 63;
    int fm = lane & 15, fq = lane >> 4;
    int kb0 = blockIdx.x * 128;
    f32x4 acc[2][4] = {};
#pragma unroll
    for (int ks = 0; ks < 128; ks += 32) {
        int k = kb0 + ks + fq * 8;
        bf16x8 a0 = *(const bf16x8*)(EMB + (size_t)fm * 131072 + k);
        bf16x8 a1 = *(const bf16x8*)(EMB + (size_t)(16 + fm) * 131072 + k);
        bf16x8 bfr[4];
#pragma unroll
        for (int j = 0; j < 4; j++) {
            int n = wave * 64 + j * 16 + fm;
            const float* p = W1 + (size_t)n * 131072 + k;
            float4 lo = *(const float4*)p;
            float4 hi = *(const float4*)(p + 4);
            bf16x8 b = {(bf16_t)lo.x, (bf16_t)lo.y, (bf16_t)lo.z, (bf16_t)lo.w,
                        (bf16_t)hi.x, (bf16_t)hi.y, (bf16_t)hi.z, (bf16_t)hi.w};
            bfr[j] = b;
        }
#pragma unroll
        for (int j = 0; j < 4; j++) {
            acc[0][j] = __builtin_amdgcn_mfma_f32_16x16x32_bf16(a0, bfr[j], acc[0][j], 0, 0, 0);
            acc[1][j] = __builtin_amdgcn_mfma_f32_16x16x32_bf16(a1, bfr[j], acc[1][j], 0, 0, 0);
        }
    }
    float* P = partials + (size_t)blockIdx.x * 8192;
#pragma unroll
    for (int i = 0; i < 2; i++)
#pragma unroll
        for (int j = 0; j < 4; j++)
#pragma unroll
            for (int r = 0; r < 4; r++)
                P[(size_t)(i * 16 + fq * 4 + r) * 256 + wave * 64 + j * 16 + fm] = acc[i][j][r];
}

// reduce 1024 partials -> 8 (grid-wide, coalesced)
__global__ __launch_bounds__(256) void k_reduce(const float* __restrict__ partials, float* __restrict__ part2) {
    int kg = blockIdx.x >> 5, eb = blockIdx.x & 31;
    int e = eb * 256 + threadIdx.x;
    float s = 0;
#pragma unroll 8
    for (int i = 0; i < 128; i++) s += partials[(size_t)(kg * 128 + i) * 8192 + e];
    part2[(size_t)kg * 8192 + e] = s;
}

// final: h1 = leaky(sum part2 + b1); h2 = leaky(h1@W2^T+b2); out = h2@W3^T+b3
__global__ __launch_bounds__(256) void k_head(const float* __restrict__ part2, const float* __restrict__ b1,
                                              const float* __restrict__ W2, const float* __restrict__ b2,
                                              const float* __restrict__ W3, const float* __restrict__ b3,
                                              float* __restrict__ out) {
    __shared__ float h1s[32][256];
    __shared__ float h2s[32][32];
    int t = threadIdx.x;
    for (int i = 0; i < 32; i++) {
        int e = i * 256 + t;
        float s = 0;
#pragma unroll
        for (int kg = 0; kg < 8; kg++) s += part2[kg * 8192 + e];
        s += b1[t];
        h1s[i][t] = (s > 0.f) ? s : 0.2f * s;
    }
    __syncthreads();
    for (int p = 0; p < 4; p++) {
        int id = p * 256 + t, si = id >> 5, o2 = id & 31;
        float s = 0;
        for (int k = 0; k < 256; k++) s += h1s[si][k] * W2[o2 * 256 + k];
        s += b2[o2];
        h2s[si][o2] = (s > 0.f) ? s : 0.2f * s;
    }
    __syncthreads();
    if (t < 64) {
        int si = t >> 1, o3 = t & 1;
        float s = 0;
#pragma unroll
        for (int k = 0; k < 32; k++) s += h2s[si][k] * W3[o3 * 32 + k];
        out[si * 2 + o3] = s + b3[o3];
    }
}

// ---------------- launcher ----------------

extern "C" void kernel_launch(void* const* d_in, const int* in_sizes, int n_in,
                              void* d_out, int out_size, void* d_ws, size_t ws_size,
                              hipStream_t stream) {
    const float* x = (const float*)d_in[0];
    const float* t = (const float*)d_in[1];
    const float* gum = (const float*)d_in[2];
    const int* eidx = (const int*)d_in[3];
    const float* c1w = (const float*)d_in[4];
    const float* c1b = (const float*)d_in[5];
    const float* c2w = (const float*)d_in[6];
    const float* c2b = (const float*)d_in[7];
    const float* fcw = (const float*)d_in[8];
    const float* fcb = (const float*)d_in[9];
    const float* w1 = (const float*)d_in[10];
    const float* b1 = (const float*)d_in[11];
    const float* w2 = (const float*)d_in[12];
    const float* b2 = (const float*)d_in[13];
    const float* w3 = (const float*)d_in[14];
    const float* b3 = (const float*)d_in[15];
    float* out = (float*)d_out;
    (void)in_sizes; (void)n_in; (void)out_size; (void)ws_size;

    char* ws = (char*)d_ws;
    size_t off = 0;
    auto alloc = [&](size_t bytes) -> char* {
        char* p = ws + off;
        off += (bytes + 255) & ~size_t(255);
        return p;
    };
    bf16_t* c1wb = (bf16_t*)alloc((size_t)256 * 512 * 2);
    bf16_t* c2wb = (bf16_t*)alloc((size_t)128 * 256 * 2);
    float4* lsr = (float4*)alloc((size_t)kNTOT * 16);
    bf16_t* AT = (bf16_t*)alloc((size_t)kBZ * kN * kN * 2);          // 16.8 MB
    float* degsum = (float*)alloc((size_t)kNTOT * 4);
    bf16_t* XW1_EMB = (bf16_t*)alloc((size_t)kNTOT * 256 * 2);       // 8.4 MB (XW1 then EMB)
    bf16_t* Z1T = (bf16_t*)alloc((size_t)kBZ * 256 * 512 * 2);       // 8.4 MB
    bf16_t* H = (bf16_t*)alloc((size_t)32768 * 256 * 2);             // 16.8 MB
    bf16_t* XW2 = (bf16_t*)alloc((size_t)32768 * 128 * 2);           // 8.4 MB
    bf16_t* Z2T = (bf16_t*)alloc((size_t)kBZ * 128 * 512 * 2);       // 4.2 MB
    int* counts = (int*)alloc((size_t)kNTOT * 4);
    int* offsets = (int*)alloc((size_t)kNTOT * 4);
    int* cursor = (int*)alloc((size_t)kNTOT * 4);
    float* diss = (float*)alloc((size_t)kNTOT * 4);
    int* list = (int*)alloc((size_t)kE * 4);
    float* partials = (float*)alloc((size_t)1024 * 8192 * 4);        // 33.5 MB
    float* part2 = (float*)alloc((size_t)8 * 8192 * 4);

    bf16_t* XW1 = XW1_EMB;
    bf16_t* EMB = XW1_EMB;  // EMB written only after XW1's last read (sparse L1)

    k_cvt3<<<192, 256, 0, stream>>>(c1w, c2w, c1wb, c2wb, counts, degsum);
    k_lsr<<<4096, 256, 0, stream>>>(t, fcw, fcb, lsr);
    k_adj<<<dim3(8, 8, 32), 256, 0, stream>>>(gum, lsr, AT, degsum);
    // sparse CSR build
    k_hist<<<2048, 256, 0, stream>>>(eidx + kE, counts);
    k_scan<<<1, 256, 0, stream>>>(counts, offsets, cursor, diss);
    k_fill<<<2048, 256, 0, stream>>>(eidx, eidx + kE, cursor, list);
    // XW1 = x @ conv1_w^T (fp32 A converted in-staging) + Z1T scaled transpose
    k_gemmT<true, 256, kNTOT><<<dim3(128, 2, 1), 256, 0, stream>>>(x, c1wb, XW1, Z1T, 512, degsum);
    // dense layer 1: H[dense] = relu(dis*(AT@Z1) + b1)
    k_gemm<1><<<dim3(4, 2, 32), 256, 0, stream>>>(AT, Z1T, H, 512, 512, 512, 256,
                                                  (size_t)512 * 512, (size_t)256 * 512, (size_t)512 * 256,
                                                  degsum, c1b);
    // sparse layer 1 -> H rows 16384..
    k_sagg<256, true><<<2048, 256, 0, stream>>>(XW1, 0, list, offsets, counts, diss, c1b,
                                                H + (size_t)16384 * 256, 0);
    // stacked layer-2 matmul: XW2 = H @ conv2_w^T (+ Z2T for dense rows)
    k_gemmT<false, 128, kNTOT><<<dim3(256, 1, 1), 256, 0, stream>>>(H, c2wb, XW2, Z2T, 256, degsum);
    // dense layer 2 -> EMB cols 0..127
    k_gemm<2><<<dim3(4, 1, 32), 256, 0, stream>>>(AT, Z2T, EMB, 512, 512, 512, 256,
                                                  (size_t)512 * 512, (size_t)128 * 512, (size_t)512 * 256,
                                                  degsum, c2b);
    // sparse layer 2 -> EMB cols 128..255
    k_sagg<128, false><<<1024, 256, 0, stream>>>(XW2, 16384, list, offsets, counts, diss, c2b, EMB, 128);
    // FCN head
    k_fcn1<<<1024, 256, 0, stream>>>(EMB, w1, partials);
    k_reduce<<<256, 256, 0, stream>>>(partials, part2);
    k_head<<<1, 256, 0, stream>>>(part2, b1, w2, b2, w3, b3, out);
}